// Round 1
// baseline (458.232 us; speedup 1.0000x reference)
//
#include <hip/hip_runtime.h>

// GraphSAGE 3-layer forward on MI355X.
// Pipeline per launch (all on `stream`, graph-capture-safe):
//  1. memset deg=0; histogram deg[dst]++ (int atomics)
//  2. single-block scan -> row_ptr (exclusive), cursor copy, deg_inv
//  3. counting-sort scatter -> edge_src (CSR by dst)
//  4. pull aggregation (atomic-free) + fused fp32 GEMM per layer

#define EMB 128

// ---------------- CSR build ----------------

__global__ void count_deg_kernel(const int* __restrict__ dst, int* __restrict__ deg, int e) {
    int i = blockIdx.x * blockDim.x + threadIdx.x;
    if (i < e) atomicAdd(&deg[dst[i]], 1);
}

__global__ __launch_bounds__(1024) void scan_kernel(const int* __restrict__ deg,
                                                    int* __restrict__ row_ptr,
                                                    int* __restrict__ cursor,
                                                    float* __restrict__ deg_inv, int n) {
    __shared__ int lds[1024];
    const int t = threadIdx.x;
    const int CH = (n + 1023) >> 10;
    const int base = t * CH;
    int sum = 0;
    for (int i = 0; i < CH; ++i) {
        int idx = base + i;
        if (idx < n) sum += deg[idx];
    }
    lds[t] = sum;
    __syncthreads();
    int incl = sum;
    for (int off = 1; off < 1024; off <<= 1) {
        int v = (t >= off) ? lds[t - off] : 0;
        __syncthreads();
        incl += v;
        lds[t] = incl;
        __syncthreads();
    }
    int run = incl - sum;  // exclusive prefix at chunk start
    for (int i = 0; i < CH; ++i) {
        int idx = base + i;
        if (idx < n) {
            row_ptr[idx] = run;
            cursor[idx] = run;
            int d = deg[idx];
            deg_inv[idx] = (d > 0) ? 1.0f / (float)d : 0.0f;
            run += d;
        }
    }
    if (t == 1023) row_ptr[n] = incl;  // total = E
}

__global__ void fill_csr_kernel(const int* __restrict__ src, const int* __restrict__ dst,
                                int* __restrict__ cursor, int* __restrict__ edge_src, int e) {
    int i = blockIdx.x * blockDim.x + threadIdx.x;
    if (i < e) {
        int p = atomicAdd(&cursor[dst[i]], 1);
        edge_src[p] = src[i];
    }
}

// ---------------- aggregation ----------------

// d_in = 8 (layer 1): one thread per node.
__global__ void agg8_kernel(const float* __restrict__ x, const int* __restrict__ row_ptr,
                            const int* __restrict__ edge_src, const float* __restrict__ deg_inv,
                            float* __restrict__ agg, int n) {
    int node = blockIdx.x * blockDim.x + threadIdx.x;
    if (node >= n) return;
    int s0 = row_ptr[node], s1 = row_ptr[node + 1];
    float a0 = 0.f, a1 = 0.f, a2 = 0.f, a3 = 0.f, a4 = 0.f, a5 = 0.f, a6 = 0.f, a7 = 0.f;
    for (int e = s0; e < s1; ++e) {
        int s = edge_src[e];
        const float4 v0 = *(const float4*)(x + (size_t)s * 8);
        const float4 v1 = *(const float4*)(x + (size_t)s * 8 + 4);
        a0 += v0.x; a1 += v0.y; a2 += v0.z; a3 += v0.w;
        a4 += v1.x; a5 += v1.y; a6 += v1.z; a7 += v1.w;
    }
    float di = deg_inv[node];
    float4 r0 = make_float4(a0 * di, a1 * di, a2 * di, a3 * di);
    float4 r1 = make_float4(a4 * di, a5 * di, a6 * di, a7 * di);
    *(float4*)(agg + (size_t)node * 8) = r0;
    *(float4*)(agg + (size_t)node * 8 + 4) = r1;
}

// d_in = 128: one wave per node, lane covers 2 channels (float2 -> 512B/edge coalesced).
__global__ __launch_bounds__(256) void agg128_kernel(const float* __restrict__ h,
                                                     const int* __restrict__ row_ptr,
                                                     const int* __restrict__ edge_src,
                                                     const float* __restrict__ deg_inv,
                                                     float* __restrict__ agg, int n) {
    const int wave = threadIdx.x >> 6;
    const int lane = threadIdx.x & 63;
    const int node = blockIdx.x * 4 + wave;
    if (node >= n) return;
    const int s0 = row_ptr[node];
    const int s1 = row_ptr[node + 1];
    float ax = 0.f, ay = 0.f;
    int e = s0;
    // unroll by 2 for load ILP
    for (; e + 2 <= s1; e += 2) {
        int sa = edge_src[e];
        int sb = edge_src[e + 1];
        const float2 va = *(const float2*)(h + (size_t)sa * EMB + lane * 2);
        const float2 vb = *(const float2*)(h + (size_t)sb * EMB + lane * 2);
        ax += va.x + vb.x;
        ay += va.y + vb.y;
    }
    if (e < s1) {
        int sa = edge_src[e];
        const float2 va = *(const float2*)(h + (size_t)sa * EMB + lane * 2);
        ax += va.x;
        ay += va.y;
    }
    const float di = deg_inv[node];
    float2 r = make_float2(ax * di, ay * di);
    *(float2*)(agg + (size_t)node * EMB + lane * 2) = r;
}

// ---------------- fused GEMM: out = act(A@Wl + B@Wr + bias (+ B-row skip)) ----------------
// A,B: [n, K]; Wl,Wr: [K, 128]; out: [n, 128]
// Block: 256 threads; 32 rows/block; thread (tx=t&31, ty=t>>5) owns cols tx*4..+3,
// rows rb+ty+8i (i=0..3). Weights read from global (L2-resident), A/B staged in LDS.

template <int K, bool RELU, bool SKIP>
__global__ __launch_bounds__(256) void fused_gemm_kernel(const float* __restrict__ A,
                                                         const float* __restrict__ B,
                                                         const float* __restrict__ Wl,
                                                         const float* __restrict__ Wr,
                                                         const float* __restrict__ bias,
                                                         float* __restrict__ out, int n) {
    __shared__ float As[32][K];
    __shared__ float Bs[32][K];
    const int t = threadIdx.x;
    const int rb = blockIdx.x * 32;

    const int total4 = 32 * K / 4;
    for (int j = t; j < total4; j += 256) {
        int row = (j * 4) / K;
        int col = (j * 4) % K;
        int r = rb + row;
        float4 va = make_float4(0.f, 0.f, 0.f, 0.f);
        float4 vb = va;
        if (r < n) {
            va = *(const float4*)(A + (size_t)r * K + col);
            vb = *(const float4*)(B + (size_t)r * K + col);
        }
        *(float4*)&As[row][col] = va;
        *(float4*)&Bs[row][col] = vb;
    }
    __syncthreads();

    const int tx = t & 31;
    const int ty = t >> 5;
    const int c0 = tx * 4;

    const float4 bv = *(const float4*)(bias + c0);
    float4 acc[4] = {bv, bv, bv, bv};

#pragma unroll 2
    for (int k = 0; k < K; k += 4) {
        float4 a4[4], b4[4];
#pragma unroll
        for (int i = 0; i < 4; ++i) {
            a4[i] = *(const float4*)&As[ty + 8 * i][k];
            b4[i] = *(const float4*)&Bs[ty + 8 * i][k];
        }
#pragma unroll
        for (int kk = 0; kk < 4; ++kk) {
            const float4 wl = *(const float4*)(Wl + (size_t)(k + kk) * EMB + c0);
            const float4 wr = *(const float4*)(Wr + (size_t)(k + kk) * EMB + c0);
#pragma unroll
            for (int i = 0; i < 4; ++i) {
                const float av = ((const float*)&a4[i])[kk];
                const float bvv = ((const float*)&b4[i])[kk];
                acc[i].x = fmaf(av, wl.x, acc[i].x);
                acc[i].y = fmaf(av, wl.y, acc[i].y);
                acc[i].z = fmaf(av, wl.z, acc[i].z);
                acc[i].w = fmaf(av, wl.w, acc[i].w);
                acc[i].x = fmaf(bvv, wr.x, acc[i].x);
                acc[i].y = fmaf(bvv, wr.y, acc[i].y);
                acc[i].z = fmaf(bvv, wr.z, acc[i].z);
                acc[i].w = fmaf(bvv, wr.w, acc[i].w);
            }
        }
    }

#pragma unroll
    for (int i = 0; i < 4; ++i) {
        int r = rb + ty + 8 * i;
        if (r < n) {
            float4 v = acc[i];
            if (SKIP) {
                // skip connection = the B operand's own row (h_prev); only valid for K==128
                const float4 s = *(const float4*)&Bs[ty + 8 * i][(K == EMB) ? c0 : 0];
                v.x += s.x; v.y += s.y; v.z += s.z; v.w += s.w;
            }
            if (RELU) {
                v.x = fmaxf(v.x, 0.f);
                v.y = fmaxf(v.y, 0.f);
                v.z = fmaxf(v.z, 0.f);
                v.w = fmaxf(v.w, 0.f);
            }
            *(float4*)(out + (size_t)r * EMB + c0) = v;
        }
    }
}

// ---------------- launcher ----------------

extern "C" void kernel_launch(void* const* d_in, const int* in_sizes, int n_in,
                              void* d_out, int out_size, void* d_ws, size_t ws_size,
                              hipStream_t stream) {
    const float* x   = (const float*)d_in[0];
    const int*   src = (const int*)d_in[1];
    const int*   dst = (const int*)d_in[2];
    const float* W1l = (const float*)d_in[3];
    const float* W1r = (const float*)d_in[4];
    const float* b1  = (const float*)d_in[5];
    const float* W2l = (const float*)d_in[6];
    const float* W2r = (const float*)d_in[7];
    const float* b2  = (const float*)d_in[8];
    const float* W3l = (const float*)d_in[9];
    const float* W3r = (const float*)d_in[10];
    const float* b3  = (const float*)d_in[11];
    float* out = (float*)d_out;

    const int N = in_sizes[0] / 8;
    const int E = in_sizes[1];

    // workspace layout (all 256B-aligned by construction)
    char* ws = (char*)d_ws;
    const size_t hbytes = (size_t)N * EMB * sizeof(float);  // 25,600,000
    float* h1  = (float*)ws;
    float* h2  = (float*)(ws + hbytes);
    float* agg = (float*)(ws + 2 * hbytes);
    int* deg      = (int*)(ws + 3 * hbytes);
    int* row_ptr  = deg + N;
    int* cursor   = row_ptr + N + 1;
    float* deg_inv = (float*)(cursor + N);
    int* edge_src = (int*)(deg_inv + N);

    // 1. degree histogram
    hipMemsetAsync(deg, 0, (size_t)N * sizeof(int), stream);
    count_deg_kernel<<<(E + 255) / 256, 256, 0, stream>>>(dst, deg, E);
    // 2. scan -> row_ptr, cursor, deg_inv
    scan_kernel<<<1, 1024, 0, stream>>>(deg, row_ptr, cursor, deg_inv, N);
    // 3. scatter -> edge_src
    fill_csr_kernel<<<(E + 255) / 256, 256, 0, stream>>>(src, dst, cursor, edge_src, E);

    const int gemm_grid = (N + 31) / 32;
    const int agg_grid = (N + 3) / 4;

    // layer 1: h1 = relu(agg8(x)@W1l + x@W1r + b1)
    agg8_kernel<<<(N + 255) / 256, 256, 0, stream>>>(x, row_ptr, edge_src, deg_inv, agg, N);
    fused_gemm_kernel<8, true, false><<<gemm_grid, 256, 0, stream>>>(agg, x, W1l, W1r, b1, h1, N);

    // layer 2: h2 = relu(agg(h1)@W2l + h1@W2r + b2 + h1)
    agg128_kernel<<<agg_grid, 256, 0, stream>>>(h1, row_ptr, edge_src, deg_inv, agg, N);
    fused_gemm_kernel<128, true, true><<<gemm_grid, 256, 0, stream>>>(agg, h1, W2l, W2r, b2, h2, N);

    // layer 3: out = agg(h2)@W3l + h2@W3r + b3 + h2
    agg128_kernel<<<agg_grid, 256, 0, stream>>>(h2, row_ptr, edge_src, deg_inv, agg, N);
    fused_gemm_kernel<128, false, true><<<gemm_grid, 256, 0, stream>>>(agg, h2, W3l, W3r, b3, out, N);
}

// Round 2
// 310.930 us; speedup vs baseline: 1.4737x; 1.4737x over previous
//
#include <hip/hip_runtime.h>

// GraphSAGE 3-layer forward on MI355X.
// Pipeline per launch (all on `stream`, graph-capture-safe):
//  1. memset deg=0; histogram deg[dst]++ (int atomics)
//  2. two-level multi-block scan -> row_ptr (exclusive), cursor copy, deg_inv
//  3. counting-sort scatter -> edge_src (CSR by dst)
//  4. pull aggregation (atomic-free) + fused fp32 GEMM per layer

#define EMB 128
#define SCAN_CHUNK 1024  // elements per block in the scan (256 thr x 4)

// ---------------- CSR build ----------------

__global__ void count_deg_kernel(const int* __restrict__ dst, int* __restrict__ deg, int e) {
    int i = blockIdx.x * blockDim.x + threadIdx.x;
    if (i < e) atomicAdd(&deg[dst[i]], 1);
}

__device__ __forceinline__ int wave_incl_scan(int v, int lane) {
#pragma unroll
    for (int off = 1; off < 64; off <<= 1) {
        int u = __shfl_up(v, off);
        if (lane >= off) v += u;
    }
    return v;
}

// Kernel A: per-block sums of deg (SCAN_CHUNK elements/block)
__global__ __launch_bounds__(256) void partial_sum_kernel(const int* __restrict__ deg,
                                                          int* __restrict__ partials, int n) {
    const int t = threadIdx.x;
    const int base = blockIdx.x * SCAN_CHUNK + t * 4;
    int s = 0;
    if (base + 3 < n) {
        int4 v = *(const int4*)(deg + base);
        s = v.x + v.y + v.z + v.w;
    } else {
        for (int i = 0; i < 4; ++i)
            if (base + i < n) s += deg[base + i];
    }
    const int lane = t & 63, wid = t >> 6;
#pragma unroll
    for (int off = 32; off > 0; off >>= 1) s += __shfl_down(s, off);
    __shared__ int wsum[4];
    if (lane == 0) wsum[wid] = s;
    __syncthreads();
    if (t == 0) partials[blockIdx.x] = wsum[0] + wsum[1] + wsum[2] + wsum[3];
}

// Kernel B: single-block exclusive scan of the (<=256) partials; writes row_ptr[n]=E.
__global__ __launch_bounds__(256) void scan_partials_kernel(int* __restrict__ partials, int nb,
                                                            int* __restrict__ row_ptr, int n) {
    const int t = threadIdx.x;
    int v = (t < nb) ? partials[t] : 0;
    const int lane = t & 63, wid = t >> 6;
    int incl = wave_incl_scan(v, lane);
    __shared__ int wsum[4];
    if (lane == 63) wsum[wid] = incl;
    __syncthreads();
    int woff = 0;
    for (int w = 0; w < wid; ++w) woff += wsum[w];
    incl += woff;
    if (t < nb) partials[t] = incl - v;  // exclusive
    if (t == nb - 1) row_ptr[n] = incl;  // total edge count
}

// Kernel C: final scan — per-block exclusive scan + block offset; writes
// row_ptr, cursor, deg_inv.
__global__ __launch_bounds__(256) void scan_final_kernel(const int* __restrict__ deg,
                                                         const int* __restrict__ partials,
                                                         int* __restrict__ row_ptr,
                                                         int* __restrict__ cursor,
                                                         float* __restrict__ deg_inv, int n) {
    const int t = threadIdx.x;
    const int base = blockIdx.x * SCAN_CHUNK + t * 4;
    int d[4] = {0, 0, 0, 0};
    if (base + 3 < n) {
        int4 v = *(const int4*)(deg + base);
        d[0] = v.x; d[1] = v.y; d[2] = v.z; d[3] = v.w;
    } else {
        for (int i = 0; i < 4; ++i)
            if (base + i < n) d[i] = deg[base + i];
    }
    const int tsum = d[0] + d[1] + d[2] + d[3];
    const int lane = t & 63, wid = t >> 6;
    int incl = wave_incl_scan(tsum, lane);
    __shared__ int wsum[4];
    if (lane == 63) wsum[wid] = incl;
    __syncthreads();
    int off = partials[blockIdx.x];
    for (int w = 0; w < wid; ++w) off += wsum[w];
    int run = off + incl - tsum;  // exclusive prefix at this thread's first element
#pragma unroll
    for (int i = 0; i < 4; ++i) {
        int idx = base + i;
        if (idx < n) {
            row_ptr[idx] = run;
            cursor[idx] = run;
            deg_inv[idx] = (d[i] > 0) ? 1.0f / (float)d[i] : 0.0f;
            run += d[i];
        }
    }
}

__global__ void fill_csr_kernel(const int* __restrict__ src, const int* __restrict__ dst,
                                int* __restrict__ cursor, int* __restrict__ edge_src, int e) {
    int i = blockIdx.x * blockDim.x + threadIdx.x;
    if (i < e) {
        int p = atomicAdd(&cursor[dst[i]], 1);
        edge_src[p] = src[i];
    }
}

// ---------------- aggregation ----------------

// d_in = 8 (layer 1): one thread per node.
__global__ void agg8_kernel(const float* __restrict__ x, const int* __restrict__ row_ptr,
                            const int* __restrict__ edge_src, const float* __restrict__ deg_inv,
                            float* __restrict__ agg, int n) {
    int node = blockIdx.x * blockDim.x + threadIdx.x;
    if (node >= n) return;
    int s0 = row_ptr[node], s1 = row_ptr[node + 1];
    float a0 = 0.f, a1 = 0.f, a2 = 0.f, a3 = 0.f, a4 = 0.f, a5 = 0.f, a6 = 0.f, a7 = 0.f;
    for (int e = s0; e < s1; ++e) {
        int s = edge_src[e];
        const float4 v0 = *(const float4*)(x + (size_t)s * 8);
        const float4 v1 = *(const float4*)(x + (size_t)s * 8 + 4);
        a0 += v0.x; a1 += v0.y; a2 += v0.z; a3 += v0.w;
        a4 += v1.x; a5 += v1.y; a6 += v1.z; a7 += v1.w;
    }
    float di = deg_inv[node];
    float4 r0 = make_float4(a0 * di, a1 * di, a2 * di, a3 * di);
    float4 r1 = make_float4(a4 * di, a5 * di, a6 * di, a7 * di);
    *(float4*)(agg + (size_t)node * 8) = r0;
    *(float4*)(agg + (size_t)node * 8 + 4) = r1;
}

// d_in = 128: one wave per node, lane covers 2 channels (float2 -> 512B/edge
// coalesced). 4-wide edge unroll for memory-level parallelism (gather is
// latency-bound: avg degree ~12).
__global__ __launch_bounds__(256) void agg128_kernel(const float* __restrict__ h,
                                                     const int* __restrict__ row_ptr,
                                                     const int* __restrict__ edge_src,
                                                     const float* __restrict__ deg_inv,
                                                     float* __restrict__ agg, int n) {
    const int wave = threadIdx.x >> 6;
    const int lane = threadIdx.x & 63;
    const int node = blockIdx.x * 4 + wave;
    if (node >= n) return;
    const int s0 = row_ptr[node];
    const int s1 = row_ptr[node + 1];
    float ax = 0.f, ay = 0.f;
    int e = s0;
    for (; e + 4 <= s1; e += 4) {
        const int sa = edge_src[e];
        const int sb = edge_src[e + 1];
        const int sc = edge_src[e + 2];
        const int sd = edge_src[e + 3];
        const float2 va = *(const float2*)(h + (size_t)sa * EMB + lane * 2);
        const float2 vb = *(const float2*)(h + (size_t)sb * EMB + lane * 2);
        const float2 vc = *(const float2*)(h + (size_t)sc * EMB + lane * 2);
        const float2 vd = *(const float2*)(h + (size_t)sd * EMB + lane * 2);
        ax += (va.x + vb.x) + (vc.x + vd.x);
        ay += (va.y + vb.y) + (vc.y + vd.y);
    }
    for (; e < s1; ++e) {
        const int sa = edge_src[e];
        const float2 va = *(const float2*)(h + (size_t)sa * EMB + lane * 2);
        ax += va.x;
        ay += va.y;
    }
    const float di = deg_inv[node];
    float2 r = make_float2(ax * di, ay * di);
    *(float2*)(agg + (size_t)node * EMB + lane * 2) = r;
}

// ---------------- fused GEMM: out = act(A@Wl + B@Wr + bias (+ B-row skip)) ----------------
// A,B: [n, K]; Wl,Wr: [K, 128]; out: [n, 128]
// Block: 256 threads; 32 rows/block; thread (tx=t&31, ty=t>>5) owns cols tx*4..+3,
// rows rb+ty+8i (i=0..3). Weights read from global (L2-resident), A/B staged in LDS.

template <int K, bool RELU, bool SKIP>
__global__ __launch_bounds__(256) void fused_gemm_kernel(const float* __restrict__ A,
                                                         const float* __restrict__ B,
                                                         const float* __restrict__ Wl,
                                                         const float* __restrict__ Wr,
                                                         const float* __restrict__ bias,
                                                         float* __restrict__ out, int n) {
    __shared__ float As[32][K];
    __shared__ float Bs[32][K];
    const int t = threadIdx.x;
    const int rb = blockIdx.x * 32;

    const int total4 = 32 * K / 4;
    for (int j = t; j < total4; j += 256) {
        int row = (j * 4) / K;
        int col = (j * 4) % K;
        int r = rb + row;
        float4 va = make_float4(0.f, 0.f, 0.f, 0.f);
        float4 vb = va;
        if (r < n) {
            va = *(const float4*)(A + (size_t)r * K + col);
            vb = *(const float4*)(B + (size_t)r * K + col);
        }
        *(float4*)&As[row][col] = va;
        *(float4*)&Bs[row][col] = vb;
    }
    __syncthreads();

    const int tx = t & 31;
    const int ty = t >> 5;
    const int c0 = tx * 4;

    const float4 bv = *(const float4*)(bias + c0);
    float4 acc[4] = {bv, bv, bv, bv};

#pragma unroll 2
    for (int k = 0; k < K; k += 4) {
        float4 a4[4], b4[4];
#pragma unroll
        for (int i = 0; i < 4; ++i) {
            a4[i] = *(const float4*)&As[ty + 8 * i][k];
            b4[i] = *(const float4*)&Bs[ty + 8 * i][k];
        }
#pragma unroll
        for (int kk = 0; kk < 4; ++kk) {
            const float4 wl = *(const float4*)(Wl + (size_t)(k + kk) * EMB + c0);
            const float4 wr = *(const float4*)(Wr + (size_t)(k + kk) * EMB + c0);
#pragma unroll
            for (int i = 0; i < 4; ++i) {
                const float av = ((const float*)&a4[i])[kk];
                const float bvv = ((const float*)&b4[i])[kk];
                acc[i].x = fmaf(av, wl.x, acc[i].x);
                acc[i].y = fmaf(av, wl.y, acc[i].y);
                acc[i].z = fmaf(av, wl.z, acc[i].z);
                acc[i].w = fmaf(av, wl.w, acc[i].w);
                acc[i].x = fmaf(bvv, wr.x, acc[i].x);
                acc[i].y = fmaf(bvv, wr.y, acc[i].y);
                acc[i].z = fmaf(bvv, wr.z, acc[i].z);
                acc[i].w = fmaf(bvv, wr.w, acc[i].w);
            }
        }
    }

#pragma unroll
    for (int i = 0; i < 4; ++i) {
        int r = rb + ty + 8 * i;
        if (r < n) {
            float4 v = acc[i];
            if (SKIP) {
                // skip connection = the B operand's own row (h_prev); only valid for K==128
                const float4 s = *(const float4*)&Bs[ty + 8 * i][(K == EMB) ? c0 : 0];
                v.x += s.x; v.y += s.y; v.z += s.z; v.w += s.w;
            }
            if (RELU) {
                v.x = fmaxf(v.x, 0.f);
                v.y = fmaxf(v.y, 0.f);
                v.z = fmaxf(v.z, 0.f);
                v.w = fmaxf(v.w, 0.f);
            }
            *(float4*)(out + (size_t)r * EMB + c0) = v;
        }
    }
}

// ---------------- launcher ----------------

extern "C" void kernel_launch(void* const* d_in, const int* in_sizes, int n_in,
                              void* d_out, int out_size, void* d_ws, size_t ws_size,
                              hipStream_t stream) {
    const float* x   = (const float*)d_in[0];
    const int*   src = (const int*)d_in[1];
    const int*   dst = (const int*)d_in[2];
    const float* W1l = (const float*)d_in[3];
    const float* W1r = (const float*)d_in[4];
    const float* b1  = (const float*)d_in[5];
    const float* W2l = (const float*)d_in[6];
    const float* W2r = (const float*)d_in[7];
    const float* b2  = (const float*)d_in[8];
    const float* W3l = (const float*)d_in[9];
    const float* W3r = (const float*)d_in[10];
    const float* b3  = (const float*)d_in[11];
    float* out = (float*)d_out;

    const int N = in_sizes[0] / 8;
    const int E = in_sizes[1];

    // workspace layout (all 256B-aligned by construction)
    char* ws = (char*)d_ws;
    const size_t hbytes = (size_t)N * EMB * sizeof(float);  // 25,600,000
    float* h1  = (float*)ws;
    float* h2  = (float*)(ws + hbytes);
    float* agg = (float*)(ws + 2 * hbytes);
    int* deg      = (int*)(ws + 3 * hbytes);
    int* row_ptr  = deg + N;
    int* cursor   = row_ptr + N + 1;
    float* deg_inv = (float*)(cursor + N);
    int* edge_src = (int*)(deg_inv + N);
    int* partials = edge_src + E;

    const int nb = (N + SCAN_CHUNK - 1) / SCAN_CHUNK;  // 49 blocks

    // 1. degree histogram
    hipMemsetAsync(deg, 0, (size_t)N * sizeof(int), stream);
    count_deg_kernel<<<(E + 255) / 256, 256, 0, stream>>>(dst, deg, E);
    // 2. two-level scan -> row_ptr, cursor, deg_inv
    partial_sum_kernel<<<nb, 256, 0, stream>>>(deg, partials, N);
    scan_partials_kernel<<<1, 256, 0, stream>>>(partials, nb, row_ptr, N);
    scan_final_kernel<<<nb, 256, 0, stream>>>(deg, partials, row_ptr, cursor, deg_inv, N);
    // 3. scatter -> edge_src
    fill_csr_kernel<<<(E + 255) / 256, 256, 0, stream>>>(src, dst, cursor, edge_src, E);

    const int gemm_grid = (N + 31) / 32;
    const int agg_grid = (N + 3) / 4;

    // layer 1: h1 = relu(agg8(x)@W1l + x@W1r + b1)
    agg8_kernel<<<(N + 255) / 256, 256, 0, stream>>>(x, row_ptr, edge_src, deg_inv, agg, N);
    fused_gemm_kernel<8, true, false><<<gemm_grid, 256, 0, stream>>>(agg, x, W1l, W1r, b1, h1, N);

    // layer 2: h2 = relu(agg(h1)@W2l + h1@W2r + b2 + h1)
    agg128_kernel<<<agg_grid, 256, 0, stream>>>(h1, row_ptr, edge_src, deg_inv, agg, N);
    fused_gemm_kernel<128, true, true><<<gemm_grid, 256, 0, stream>>>(agg, h1, W2l, W2r, b2, h2, N);

    // layer 3: out = agg(h2)@W3l + h2@W3r + b3 + h2
    agg128_kernel<<<agg_grid, 256, 0, stream>>>(h2, row_ptr, edge_src, deg_inv, agg, N);
    fused_gemm_kernel<128, false, true><<<gemm_grid, 256, 0, stream>>>(agg, h2, W3l, W3r, b3, out, N);
}